// Round 6
// baseline (264.435 us; speedup 1.0000x reference)
//
#include <hip/hip_runtime.h>
#include <hip/hip_cooperative_groups.h>

// Voxel pooling v7: single cooperative kernel (scan + transpose + grid.sync +
// bucket + register-accumulate + spill fold-in), plus one tiny memset.
// v5/v6 post-mortem: 5-dispatch pipeline, each kernel < 44us so invisible in
// top-5; ~60us of the 136us total unattributed (launch bubbles and/or a wrong
// per-kernel model). Fusing removes 3 dispatch boundaries + the spill kernel
// (bin-exclusive output ownership lets each block fold its own bin's spills),
// and restores counter visibility: one big kernel will re-enter the top-5.

namespace cg = cooperative_groups;

namespace {
constexpr int NVX = 128, NVY = 128, C = 80;
constexpr int B = 2, N = 6, D = 112, H = 16, W = 44;
constexpr int HW    = H * W;             // 704
constexpr int BN    = B * N;             // 12
constexpr int DHW   = D * HW;            // 78848
constexpr int NDHW  = N * DHW;           // 473088
constexpr int TOTAL = B * NDHW;          // 946176
constexpr int NVOX  = B * NVY * NVX;     // 32768

constexpr int NBIN  = 256;               // bin = v & 255; also grid size
constexpr int VPB   = NVOX / NBIN;       // 128 voxels per bin (vl = v>>8)
constexpr int SLOT  = 24;                // slice: 23 data + 1 count (192B)
constexpr int CAP   = 23;
constexpr int PPB   = TOTAL / NBIN;      // 3696 points per scan block (exact)
constexpr int ACT   = PPB / 4;           // 924 active scan threads (4 pts ea)
constexpr int NTILE = BN * (C / 16) * (HW / 64);  // 660 transpose tiles
constexpr int VCAP  = 60;                // per-voxel list cap (lambda=28.9)
constexpr int OCAP  = 32;                // LDS overflow mini-list
constexpr int SPILLCAP = 65536;

// LDS union layout (single 62.5KB block, 1 block/CU):
//   scan : stage int2[256*24] = 49152 | bcnt int[256] @49152      (50176)
//   tr   : tile float[16*68]  = 4352
//   acc  : list int2[128*60] = 61440 | vcnt[128] @61440 | ocnt @61952
//          | olist int2[32] @61968                                 (62224)
constexpr int SMEM_BYTES = 62464;
}

__global__ __launch_bounds__(1024) void fused_kernel(
    const int*   __restrict__ geom, const float* __restrict__ depth,
    const float* __restrict__ ctx,  float* __restrict__ ctx_t,
    int2* __restrict__ staging, int* __restrict__ spillcnt,
    int2* __restrict__ spill,   float* __restrict__ out)
{
    __shared__ __align__(16) char smem[SMEM_BYTES];
    const int bid  = blockIdx.x;
    const int t    = threadIdx.x;
    const int wave = t >> 6, lane = t & 63;

    // ---------------- phase 1: scan 3696 points into 256 LDS bins ----------
    {
        int2* stage = (int2*)smem;                 // [256*24]
        int*  bcnt  = (int*)(smem + 49152);        // [256]
        if (t < NBIN) bcnt[t] = 0;
        __syncthreads();

        if (t < ACT) {
            const int p0 = bid * PPB + t * 4;
            const int4* g4 = (const int4*)(geom + (size_t)3 * p0);  // 48B aligned
            const int4 q0 = g4[0], q1 = g4[1], q2 = g4[2];
            const float4 dp = *(const float4*)(depth + p0);
            const int xs[4] = {q0.x, q0.w, q1.z, q2.y};
            const int ys[4] = {q0.y, q1.x, q1.w, q2.z};
            const int db[4] = {__float_as_int(dp.x), __float_as_int(dp.y),
                               __float_as_int(dp.z), __float_as_int(dp.w)};
            int bins[4], keys[4], idxv[4];
            #pragma unroll
            for (int u = 0; u < 4; ++u) {
                const int x = xs[u], y = ys[u];
                const bool ok = (unsigned)x < (unsigned)NVX &&
                                (unsigned)y < (unsigned)NVY;
                const int p  = p0 + u;
                const int b  = (p >= NDHW) ? 1 : 0;       // B == 2
                const int v  = (b * NVY + y) * NVX + x;
                const int bn = (unsigned)p / (unsigned)DHW;
                const int hw = (unsigned)p % (unsigned)HW;
                bins[u] = v & 255;
                keys[u] = (v << 14) | (bn * HW + hw);     // v:15b | row:14b
                idxv[u] = ok ? -1 : -2;
            }
            #pragma unroll
            for (int u = 0; u < 4; ++u)                   // independent atomics
                if (idxv[u] == -1) idxv[u] = atomicAdd(&bcnt[bins[u]], 1);
            #pragma unroll
            for (int u = 0; u < 4; ++u) {
                if (idxv[u] == -2) continue;
                if (idxv[u] < CAP) {
                    stage[bins[u] * SLOT + idxv[u]] = make_int2(keys[u], db[u]);
                } else {
                    int s = atomicAdd(spillcnt, 1);       // rare (~850 total)
                    if (s < SPILLCAP) spill[s] = make_int2(keys[u], db[u]);
                }
            }
        }
        __syncthreads();
        if (t < NBIN) stage[t * SLOT + CAP].x = bcnt[t];  // count in slot 23
        __syncthreads();

        // stream out 3072 int4: slice = 192B = 3 full lines, aligned
        const int4* src = (const int4*)stage;
        int4* dst = (int4*)staging;
        #pragma unroll
        for (int k = 0; k < 3; ++k) {
            const int i  = k * 1024 + t;        // 0..3071
            const int sl = i / 12, part = i - sl * 12;
            dst[((size_t)sl * NBIN + bid) * 12 + part] = src[i];
        }
    }
    __syncthreads();

    // ---------------- phase 2: ctx transpose, 1 tile/block/pass ------------
    {
        float* tile = (float*)smem;             // 16c x 68
        for (int k = 0; k < 3; ++k) {
            const int tid = k * NBIN + bid;
            if (tid < NTILE) {
                const int bn = tid / 55, rem = tid % 55;
                const int c0 = (rem / 11) * 16, hw0 = (rem % 11) * 64;
                const int c = t >> 6, hw = t & 63;       // 16c x 64hw = 1024
                tile[c * 68 + hw] =
                    ctx[(size_t)(bn * C + c0 + c) * HW + hw0 + hw];
                __syncthreads();
                const int cr = t & 15, hwr = t >> 4;     // 64hw x 16c
                ctx_t[(size_t)(bn * HW + hw0 + hwr) * C + c0 + cr] =
                    tile[cr * 68 + hwr];
                __syncthreads();
            }
        }
    }

    __threadfence();
    cg::this_grid().sync();

    // ---------------- phase 3: bucket this bin's entries into voxel lists --
    int2* list  = (int2*)smem;                  // [128*60]
    int*  vcnt  = (int*)(smem + 61440);         // [128]
    int*  ocnt  = (int*)(smem + 61952);
    int2* olist = (int2*)(smem + 61968);        // [32]
    const int bin = bid;

    if (t < VPB) vcnt[t] = 0;
    if (t == 0) *ocnt = 0;
    __syncthreads();

    {
        // 2 slices per wave-iteration: lanes 0..23 slice A, 32..55 slice B
        const bool rA = lane < 24, rB = (lane >= 32) && (lane < 56);
        const int slot = rA ? lane : lane - 32;
        for (int pr = wave; pr < NBIN / 2; pr += 16) {
            const int blk = pr * 2 + (rB ? 1 : 0);
            int2 e = make_int2(0, 0);
            if (rA || rB)
                e = staging[((size_t)bin * NBIN + blk) * SLOT + slot];
            int cA = __shfl(e.x, 23), cB = __shfl(e.x, 55);
            cA = cA < CAP ? cA : CAP;
            cB = cB < CAP ? cB : CAP;
            const bool val = (rA && slot < cA) || (rB && slot < cB);
            if (val) {
                const int vl  = e.x >> 22;      // v>>8
                const int idx = atomicAdd(&vcnt[vl], 1);
                if (idx < VCAP) list[vl * VCAP + idx] = e;
                else { int o = atomicAdd(ocnt, 1); if (o < OCAP) olist[o] = e; }
            }
        }
        // fold global scan-spills belonging to this bin (~850 total entries)
        int scnt = *spillcnt;
        scnt = scnt < SPILLCAP ? scnt : SPILLCAP;
        for (int i = t; i < scnt; i += 1024) {
            int2 e = spill[i];
            if (((e.x >> 14) & 255) == bin) {
                const int vl  = e.x >> 22;
                const int idx = atomicAdd(&vcnt[vl], 1);
                if (idx < VCAP) list[vl * VCAP + idx] = e;
                else { int o = atomicAdd(ocnt, 1); if (o < OCAP) olist[o] = e; }
            }
        }
    }
    __syncthreads();

    // ---------------- phase 4: register accumulate, 8 voxels per wave ------
    const int off2 = 64 + (lane & 15);          // channels 64..79
    for (int vv = 0; vv < VPB / 16; ++vv) {
        const int vl = wave * (VPB / 16) + vv;
        int n = vcnt[vl];
        n = n < VCAP ? n : VCAP;
        const int2* lp = list + vl * VCAP;

        float a0 = 0.f, a1 = 0.f, a2 = 0.f, a3 = 0.f;
        float a4 = 0.f, a5 = 0.f, a6 = 0.f, a7 = 0.f;
        float b0 = 0.f, b1 = 0.f, b2 = 0.f, b3 = 0.f;
        float b4 = 0.f, b5 = 0.f, b6 = 0.f, b7 = 0.f;
        int j = 0;
        for (; j + 8 <= n; j += 8) {            // 8 chains, 16 loads in flight
            const int2 e0 = lp[j],     e1 = lp[j + 1], e2 = lp[j + 2], e3 = lp[j + 3];
            const int2 e4 = lp[j + 4], e5 = lp[j + 5], e6 = lp[j + 6], e7 = lp[j + 7];
            const float* c0 = ctx_t + (size_t)(e0.x & 16383) * C;
            const float* c1 = ctx_t + (size_t)(e1.x & 16383) * C;
            const float* c2 = ctx_t + (size_t)(e2.x & 16383) * C;
            const float* c3 = ctx_t + (size_t)(e3.x & 16383) * C;
            const float* c4 = ctx_t + (size_t)(e4.x & 16383) * C;
            const float* c5 = ctx_t + (size_t)(e5.x & 16383) * C;
            const float* c6 = ctx_t + (size_t)(e6.x & 16383) * C;
            const float* c7 = ctx_t + (size_t)(e7.x & 16383) * C;
            const float f0 = c0[lane], f1 = c1[lane], f2 = c2[lane], f3 = c3[lane];
            const float f4 = c4[lane], f5 = c5[lane], f6 = c6[lane], f7 = c7[lane];
            const float g0 = c0[off2], g1 = c1[off2], g2 = c2[off2], g3 = c3[off2];
            const float g4 = c4[off2], g5 = c5[off2], g6 = c6[off2], g7 = c7[off2];
            const float w0 = __int_as_float(e0.y), w1 = __int_as_float(e1.y);
            const float w2 = __int_as_float(e2.y), w3 = __int_as_float(e3.y);
            const float w4 = __int_as_float(e4.y), w5 = __int_as_float(e5.y);
            const float w6 = __int_as_float(e6.y), w7 = __int_as_float(e7.y);
            a0 += w0 * f0; a1 += w1 * f1; a2 += w2 * f2; a3 += w3 * f3;
            a4 += w4 * f4; a5 += w5 * f5; a6 += w6 * f6; a7 += w7 * f7;
            b0 += w0 * g0; b1 += w1 * g1; b2 += w2 * g2; b3 += w3 * g3;
            b4 += w4 * g4; b5 += w5 * g5; b6 += w6 * g6; b7 += w7 * g7;
        }
        for (; j + 4 <= n; j += 4) {
            const int2 e0 = lp[j], e1 = lp[j + 1], e2 = lp[j + 2], e3 = lp[j + 3];
            const float* c0 = ctx_t + (size_t)(e0.x & 16383) * C;
            const float* c1 = ctx_t + (size_t)(e1.x & 16383) * C;
            const float* c2 = ctx_t + (size_t)(e2.x & 16383) * C;
            const float* c3 = ctx_t + (size_t)(e3.x & 16383) * C;
            const float f0 = c0[lane], f1 = c1[lane], f2 = c2[lane], f3 = c3[lane];
            const float g0 = c0[off2], g1 = c1[off2], g2 = c2[off2], g3 = c3[off2];
            const float w0 = __int_as_float(e0.y), w1 = __int_as_float(e1.y);
            const float w2 = __int_as_float(e2.y), w3 = __int_as_float(e3.y);
            a0 += w0 * f0; a1 += w1 * f1; a2 += w2 * f2; a3 += w3 * f3;
            b0 += w0 * g0; b1 += w1 * g1; b2 += w2 * g2; b3 += w3 * g3;
        }
        for (; j < n; ++j) {
            const int2 e = lp[j];
            const float* c = ctx_t + (size_t)(e.x & 16383) * C;
            const float w = __int_as_float(e.y);
            a0 += w * c[lane];
            b0 += w * c[off2];
        }
        const float av = ((a0 + a1) + (a2 + a3)) + ((a4 + a5) + (a6 + a7));
        const float bv = ((b0 + b1) + (b2 + b3)) + ((b4 + b5) + (b6 + b7));
        float* o = out + (size_t)((vl << 8) | bin) * C;   // v = vl<<8 | bin
        o[lane] = av;
        if (lane < 16) o[64 + lane] = bv;
    }
    __syncthreads();

    // ---------------- phase 5: overflow fixup (this block owns these rows) --
    if (wave == 0) {
        int oc = *ocnt;
        oc = oc < OCAP ? oc : OCAP;
        for (int i = 0; i < oc; ++i) {
            const int2 e = olist[i];
            const int vl = e.x >> 22, row = e.x & 16383;
            const float dep = __int_as_float(e.y);
            const float* c = ctx_t + (size_t)row * C;
            float* o = out + (size_t)((vl << 8) | bin) * C;
            unsafeAtomicAdd(o + lane, dep * c[lane]);
            if (lane < 16) unsafeAtomicAdd(o + 64 + lane, dep * c[64 + lane]);
        }
    }
}

extern "C" void kernel_launch(void* const* d_in, const int* in_sizes, int n_in,
                              void* d_out, int out_size, void* d_ws, size_t ws_size,
                              hipStream_t stream) {
    const int*   geom  = (const int*)d_in[0];
    const float* depth = (const float*)d_in[1];
    const float* ctx   = (const float*)d_in[2];
    float*       out   = (float*)d_out;

    // Workspace (~15.8 MB, all segments 256B-multiple):
    char* ws = (char*)d_ws;
    int2* staging  = (int2*)ws; ws += (size_t)NBIN * NBIN * SLOT * 8;  // 12,582,912
    int2* spill    = (int2*)ws; ws += (size_t)SPILLCAP * 8;            //    524,288
    int*  spillcnt = (int*)ws;  ws += 256;
    float* ctx_t   = (float*)ws;                                       //  2,703,360

    hipMemsetAsync(spillcnt, 0, 256, stream);

    void* args[] = {(void*)&geom, (void*)&depth, (void*)&ctx, (void*)&ctx_t,
                    (void*)&staging, (void*)&spillcnt, (void*)&spill,
                    (void*)&out};
    hipLaunchCooperativeKernel((void*)fused_kernel, dim3(NBIN), dim3(1024),
                               args, 0, stream);
}

// Round 7
// 126.605 us; speedup vs baseline: 2.0887x; 2.0887x over previous
//
#include <hip/hip_runtime.h>

// Voxel pooling v8: v6 pipeline with 2x grid concurrency on scan and acc.
// v7 fused post-mortem: 168us, VALUBusy 11%, HBM 4% -> latency-bound, not
// pipe-bound; and v5/v6's scan (462 blocks = 1.8/CU) and acc (256 blocks =
// 1/CU) were starved of waves to hide latency. v8: scan = 924 blocks x 1024pts
// (512 bins, lambda=2, 64B slices, 4 blocks/CU), acc = 512 blocks (64 voxels
// each, 29.5KB LDS, 2 blocks/CU = 32 waves). Staging 15->30MB (+5us BW) is
// the price of 2x concurrency.

namespace {
constexpr int NVX = 128, NVY = 128, C = 80;
constexpr int B = 2, N = 6, D = 112, H = 16, W = 44;
constexpr int HW    = H * W;             // 704
constexpr int BN    = B * N;             // 12
constexpr int DHW   = D * HW;            // 78848
constexpr int NDHW  = N * DHW;           // 473088
constexpr int TOTAL = B * NDHW;          // 946176
constexpr int NVOX  = B * NVY * NVX;     // 32768

constexpr int NBIN  = 512;               // bin = v & 511 = (y&3)*128 + x
constexpr int VPB   = NVOX / NBIN;       // 64 voxels per bin (vl = v>>9)
constexpr int SLOT  = 8;                 // slice: 7 data + 1 count = 64B
constexpr int CAP   = 7;
constexpr int PTS_PER_BLK = 1024;        // 4 pts/thread * 256 threads
constexpr int SCAN_BLOCKS = TOTAL / PTS_PER_BLK;       // 924 (exact; b-split 462)
constexpr int TR_BLOCKS   = BN * (C / 16) * (HW / 64); // 660
constexpr int SPILLCAP = 65536;

constexpr int VCAP = 57;                 // per-voxel list cap (lambda=28.9)
}

// ---- 1a. scan: LDS-bin 1024 pts/block into 512 bins, 64B slices out ----
__global__ __launch_bounds__(256) void scan_kernel(
    const int*   __restrict__ geom, const float* __restrict__ depth,
    int2* __restrict__ staging, int* __restrict__ spillcnt,
    int2* __restrict__ spill)
{
    __shared__ int2 stage[NBIN * SLOT];   // 32 KB
    __shared__ int  bcnt[NBIN];           // 2 KB

    const int t = threadIdx.x;
    const int lane = t & 63;
    bcnt[t] = 0; bcnt[t + 256] = 0;
    __syncthreads();

    const int p0 = blockIdx.x * PTS_PER_BLK + t * 4;
    const int4* g4 = (const int4*)(geom + (size_t)3 * p0);  // 48B, 16B-aligned
    const int4 q0 = g4[0], q1 = g4[1], q2 = g4[2];
    const float4 dp = *(const float4*)(depth + p0);
    const int xs[4] = {q0.x, q0.w, q1.z, q2.y};
    const int ys[4] = {q0.y, q1.x, q1.w, q2.z};
    const int db[4] = {__float_as_int(dp.x), __float_as_int(dp.y),
                       __float_as_int(dp.z), __float_as_int(dp.w)};

    int bins[4], keys[4], idxv[4];
    #pragma unroll
    for (int u = 0; u < 4; ++u) {
        const int x = xs[u], y = ys[u];
        const bool ok = (unsigned)x < (unsigned)NVX && (unsigned)y < (unsigned)NVY;
        const int p  = p0 + u;
        const int b  = (p >= NDHW) ? 1 : 0;           // B == 2
        const int v  = (b * NVY + y) * NVX + x;
        const int bn = (unsigned)p / (unsigned)DHW;
        const int hw = (unsigned)p % (unsigned)HW;
        bins[u] = v & 511;                            // uniform within block
        keys[u] = (v << 14) | (bn * HW + hw);         // v:15b | row:14b
        idxv[u] = ok ? -1 : -2;
    }
    #pragma unroll
    for (int u = 0; u < 4; ++u)                       // independent LDS atomics
        if (idxv[u] == -1) idxv[u] = atomicAdd(&bcnt[bins[u]], 1);
    #pragma unroll
    for (int u = 0; u < 4; ++u)
        if ((unsigned)idxv[u] < (unsigned)CAP)
            stage[bins[u] * SLOT + idxv[u]] = make_int2(keys[u], db[u]);
    #pragma unroll
    for (int u = 0; u < 4; ++u) {                     // wave-aggregated spill
        const bool sp = (idxv[u] >= CAP);
        const unsigned long long m = __ballot(sp);
        if (m) {
            const int leader = (int)__ffsll((unsigned long long)m) - 1;
            int base = 0;
            if (lane == leader) base = atomicAdd(spillcnt, (int)__popcll(m));
            base = __shfl(base, leader);
            if (sp) {
                const int off = base + (int)__popcll(m & ((1ull << lane) - 1ull));
                if (off < SPILLCAP) spill[off] = make_int2(keys[u], db[u]);
            }
        }
    }
    __syncthreads();
    stage[t * SLOT + CAP].x = bcnt[t];                // counts in slot 7
    stage[(t + 256) * SLOT + CAP].x = bcnt[t + 256];
    __syncthreads();

    // stream out 2048 int4: each slice = 4 int4 = one full 64B line
    const int4* src = (const int4*)stage;
    int4* dst = (int4*)staging;
    #pragma unroll
    for (int k = 0; k < 8; ++k) {
        const int i  = k * 256 + t;           // 0..2047
        const int sl = i >> 2, part = i & 3;  // 4 int4 per slice
        dst[((size_t)sl * SCAN_BLOCKS + blockIdx.x) * 4 + part] = src[i];
    }
}

// ---- 1b. transpose ctx (bn, c, hw) -> ctx_t (bn*HW + hw, c) ----
__global__ __launch_bounds__(256) void tr_kernel(
    const float* __restrict__ ctx, float* __restrict__ ctx_t)
{
    __shared__ float tile[16 * 68];
    const int tb  = blockIdx.x;
    const int bn  = tb / 55;
    const int rem = tb % 55;
    const int c0  = (rem / 11) * 16;
    const int hw0 = (rem % 11) * 64;
    const int t = threadIdx.x;
    const int cl = t >> 6, hwl = t & 63;
    #pragma unroll
    for (int r = 0; r < 4; ++r) {
        const int c = r * 4 + cl;
        tile[c * 68 + hwl] = ctx[(size_t)(bn * C + c0 + c) * HW + hw0 + hwl];
    }
    __syncthreads();
    const int cr = t & 15, hwr = t >> 4;
    #pragma unroll
    for (int r = 0; r < 4; ++r) {
        const int hw = r * 16 + hwr;
        ctx_t[(size_t)(bn * HW + hw0 + hw) * C + c0 + cr] = tile[cr * 68 + hw];
    }
}

// ---- 2. acc: bucket into per-voxel LDS lists, then register-accumulate ----
__global__ __launch_bounds__(1024) void acc_kernel(
    const int2* __restrict__ staging, const float* __restrict__ ctx_t,
    float* __restrict__ out, int* __restrict__ spillcnt,
    int2* __restrict__ spill)
{
    __shared__ int2 list[VPB * VCAP];   // 29184 B -> 2 blocks/CU
    __shared__ int  vcnt[VPB];          //   256 B

    const int bin  = blockIdx.x;
    const int t    = threadIdx.x;
    const int wave = t >> 6, lane = t & 63;

    if (t < VPB) vcnt[t] = 0;
    __syncthreads();

    // ---- phase 1: bucket. 8 slices per 64-lane read (512B coalesced).
    const int g = lane >> 3, slot = lane & 7;
    for (int c = wave; c < (SCAN_BLOCKS + 7) / 8; c += 16) {
        const int s = c * 8 + g;
        int2 e = make_int2(0, 0);
        if (s < SCAN_BLOCKS)
            e = staging[((size_t)bin * SCAN_BLOCKS + s) * SLOT + slot];
        int cnt = __shfl(e.x, (lane & 56) | CAP);   // slot7.x = count
        cnt = cnt < CAP ? cnt : CAP;
        if (s < SCAN_BLOCKS && slot < cnt) {
            const int vl  = e.x >> 23;              // v>>9 (key = v<<14|row)
            const int idx = atomicAdd(&vcnt[vl], 1);
            if (idx < VCAP) {
                list[vl * VCAP + idx] = e;
            } else {
                int sp = atomicAdd(spillcnt, 1);
                if (sp < SPILLCAP) spill[sp] = e;
            }
        }
    }
    __syncthreads();

    // ---- phase 2: register accumulation, 4 voxels per wave, 8 chains.
    const int off2 = 64 + (lane & 15);              // channels 64..79
    for (int vv = 0; vv < VPB / 16; ++vv) {
        const int vl = wave * (VPB / 16) + vv;
        int n = vcnt[vl];
        n = n < VCAP ? n : VCAP;
        const int2* lp = list + vl * VCAP;

        float a0 = 0.f, a1 = 0.f, a2 = 0.f, a3 = 0.f;
        float a4 = 0.f, a5 = 0.f, a6 = 0.f, a7 = 0.f;
        float b0 = 0.f, b1 = 0.f, b2 = 0.f, b3 = 0.f;
        float b4 = 0.f, b5 = 0.f, b6 = 0.f, b7 = 0.f;
        int j = 0;
        for (; j + 8 <= n; j += 8) {                // 16 L2 loads in flight
            const int2 e0 = lp[j],     e1 = lp[j + 1], e2 = lp[j + 2], e3 = lp[j + 3];
            const int2 e4 = lp[j + 4], e5 = lp[j + 5], e6 = lp[j + 6], e7 = lp[j + 7];
            const float* c0 = ctx_t + (size_t)(e0.x & 16383) * C;
            const float* c1 = ctx_t + (size_t)(e1.x & 16383) * C;
            const float* c2 = ctx_t + (size_t)(e2.x & 16383) * C;
            const float* c3 = ctx_t + (size_t)(e3.x & 16383) * C;
            const float* c4 = ctx_t + (size_t)(e4.x & 16383) * C;
            const float* c5 = ctx_t + (size_t)(e5.x & 16383) * C;
            const float* c6 = ctx_t + (size_t)(e6.x & 16383) * C;
            const float* c7 = ctx_t + (size_t)(e7.x & 16383) * C;
            const float f0 = c0[lane], f1 = c1[lane], f2 = c2[lane], f3 = c3[lane];
            const float f4 = c4[lane], f5 = c5[lane], f6 = c6[lane], f7 = c7[lane];
            const float g0 = c0[off2], g1 = c1[off2], g2 = c2[off2], g3 = c3[off2];
            const float g4 = c4[off2], g5 = c5[off2], g6 = c6[off2], g7 = c7[off2];
            const float w0 = __int_as_float(e0.y), w1 = __int_as_float(e1.y);
            const float w2 = __int_as_float(e2.y), w3 = __int_as_float(e3.y);
            const float w4 = __int_as_float(e4.y), w5 = __int_as_float(e5.y);
            const float w6 = __int_as_float(e6.y), w7 = __int_as_float(e7.y);
            a0 += w0 * f0; a1 += w1 * f1; a2 += w2 * f2; a3 += w3 * f3;
            a4 += w4 * f4; a5 += w5 * f5; a6 += w6 * f6; a7 += w7 * f7;
            b0 += w0 * g0; b1 += w1 * g1; b2 += w2 * g2; b3 += w3 * g3;
            b4 += w4 * g4; b5 += w5 * g5; b6 += w6 * g6; b7 += w7 * g7;
        }
        for (; j + 4 <= n; j += 4) {
            const int2 e0 = lp[j], e1 = lp[j + 1], e2 = lp[j + 2], e3 = lp[j + 3];
            const float* c0 = ctx_t + (size_t)(e0.x & 16383) * C;
            const float* c1 = ctx_t + (size_t)(e1.x & 16383) * C;
            const float* c2 = ctx_t + (size_t)(e2.x & 16383) * C;
            const float* c3 = ctx_t + (size_t)(e3.x & 16383) * C;
            const float f0 = c0[lane], f1 = c1[lane], f2 = c2[lane], f3 = c3[lane];
            const float g0 = c0[off2], g1 = c1[off2], g2 = c2[off2], g3 = c3[off2];
            const float w0 = __int_as_float(e0.y), w1 = __int_as_float(e1.y);
            const float w2 = __int_as_float(e2.y), w3 = __int_as_float(e3.y);
            a0 += w0 * f0; a1 += w1 * f1; a2 += w2 * f2; a3 += w3 * f3;
            b0 += w0 * g0; b1 += w1 * g1; b2 += w2 * g2; b3 += w3 * g3;
        }
        for (; j < n; ++j) {
            const int2 e = lp[j];
            const float* c = ctx_t + (size_t)(e.x & 16383) * C;
            const float w = __int_as_float(e.y);
            a0 += w * c[lane];
            b0 += w * c[off2];
        }
        const float av = ((a0 + a1) + (a2 + a3)) + ((a4 + a5) + (a6 + a7));
        const float bv = ((b0 + b1) + (b2 + b3)) + ((b4 + b5) + (b6 + b7));
        float* o = out + (size_t)((vl << 9) | bin) * C;   // v = vl<<9 | bin
        o[lane] = av;
        if (lane < 16) o[64 + lane] = bv;
    }
}

// ---- 3. spill fixup (exact; ~650 entries expected) ----
__global__ __launch_bounds__(256) void spill_kernel(
    const int* __restrict__ spillcnt, const int2* __restrict__ spill,
    const float* __restrict__ ctx_t, float* __restrict__ out)
{
    const int nwaves = gridDim.x * 4;
    const int wave   = blockIdx.x * 4 + (threadIdx.x >> 6);
    const int lane   = threadIdx.x & 63;
    int cnt = *spillcnt;
    if (cnt > SPILLCAP) cnt = SPILLCAP;
    for (int i = wave; i < cnt; i += nwaves) {
        const int2 e = spill[i];
        const int v   = e.x >> 14;          // key < 2^29, positive
        const int row = e.x & 16383;
        const float dep = __int_as_float(e.y);
        const float* c = ctx_t + (size_t)row * C;
        float* o = out + (size_t)v * C;
        unsafeAtomicAdd(o + lane, dep * c[lane]);
        if (lane < C - 64) unsafeAtomicAdd(o + 64 + lane, dep * c[64 + lane]);
    }
}

extern "C" void kernel_launch(void* const* d_in, const int* in_sizes, int n_in,
                              void* d_out, int out_size, void* d_ws, size_t ws_size,
                              hipStream_t stream) {
    const int*   geom  = (const int*)d_in[0];
    const float* depth = (const float*)d_in[1];
    const float* ctx   = (const float*)d_in[2];
    float*       out   = (float*)d_out;

    // Workspace (~33.5 MB, all segments 256B-multiple):
    char* ws = (char*)d_ws;
    int2* staging  = (int2*)ws; ws += (size_t)NBIN * SCAN_BLOCKS * SLOT * 8; // 30,277,632
    int2* spill    = (int2*)ws; ws += (size_t)SPILLCAP * 8;                  //    524,288
    int*  spillcnt = (int*)ws;  ws += 256;
    float* ctx_t   = (float*)ws;                                             //  2,703,360

    hipMemsetAsync(spillcnt, 0, 256, stream);

    scan_kernel <<<dim3(SCAN_BLOCKS), dim3(256),  0, stream>>>(
                    geom, depth, staging, spillcnt, spill);
    tr_kernel   <<<dim3(TR_BLOCKS),   dim3(256),  0, stream>>>(ctx, ctx_t);
    acc_kernel  <<<dim3(NBIN),        dim3(1024), 0, stream>>>(
                    staging, ctx_t, out, spillcnt, spill);
    spill_kernel<<<dim3(64),          dim3(256),  0, stream>>>(spillcnt, spill, ctx_t, out);
}

// Round 8
// 117.982 us; speedup vs baseline: 2.2413x; 1.0731x over previous
//
#include <hip/hip_runtime.h>

// Voxel pooling v9: 3-dispatch pipeline (memset, pre=scan+tr, acc+spillfold).
// v8 accounting: fill (~45us harness re-poison) is inside dur_us; our ~82us =
// scan ~25 + tr ~4 + acc ~30 + spill ~3 + memset ~2 + ~15us of dispatch gaps
// (gap ~3us each, pinned by v5->v6 +1-dispatch delta). v9 consolidates:
// tr fused into scan kernel (block-range split), spill fixup folded into acc
// (per-bin filter of the ~700-entry global spill list; block-exclusive output
// ownership makes it race-free), and acc phase 1 gets a 1-deep prefetch so
// the staging slice load (HBM, ~600cy) hides under the process body.

namespace {
constexpr int NVX = 128, NVY = 128, C = 80;
constexpr int B = 2, N = 6, D = 112, H = 16, W = 44;
constexpr int HW    = H * W;             // 704
constexpr int BN    = B * N;             // 12
constexpr int DHW   = D * HW;            // 78848
constexpr int NDHW  = N * DHW;           // 473088
constexpr int TOTAL = B * NDHW;          // 946176
constexpr int NVOX  = B * NVY * NVX;     // 32768

constexpr int NBIN  = 512;               // bin = v & 511 = (y&3)*128 + x
constexpr int VPB   = NVOX / NBIN;       // 64 voxels per bin (vl = v>>9)
constexpr int SLOT  = 8;                 // slice: 7 data + 1 count = 64B
constexpr int CAP   = 7;
constexpr int PTS_PER_BLK = 1024;        // 4 pts/thread * 256 threads
constexpr int SCAN_BLOCKS = TOTAL / PTS_PER_BLK;       // 924
constexpr int TR_BLOCKS   = BN * (C / 16) * (HW / 64); // 660
constexpr int PRE_BLOCKS  = SCAN_BLOCKS + TR_BLOCKS;   // 1584
constexpr int SPILLCAP = 65536;

constexpr int VCAP = 57;                 // per-voxel list cap (lambda=28.9)
constexpr int OCAP = 32;                 // LDS overflow mini-list (exp ~0.03)
}

// ---- 1. pre: scan (blocks < SCAN_BLOCKS) | ctx transpose (rest) ----
__global__ __launch_bounds__(256) void pre_kernel(
    const int*   __restrict__ geom, const float* __restrict__ depth,
    const float* __restrict__ ctx,  float* __restrict__ ctx_t,
    int2* __restrict__ staging, int* __restrict__ spillcnt,
    int2* __restrict__ spill)
{
    __shared__ int2  stage[NBIN * SLOT];   // 32 KB
    __shared__ int   bcnt[NBIN];           // 2 KB
    __shared__ float tile[16 * 68];        // transpose scratch

    const int t = threadIdx.x;
    if (blockIdx.x < SCAN_BLOCKS) {
        const int lane = t & 63;
        bcnt[t] = 0; bcnt[t + 256] = 0;
        __syncthreads();

        const int p0 = blockIdx.x * PTS_PER_BLK + t * 4;
        const int4* g4 = (const int4*)(geom + (size_t)3 * p0);  // 48B aligned
        const int4 q0 = g4[0], q1 = g4[1], q2 = g4[2];
        const float4 dp = *(const float4*)(depth + p0);
        const int xs[4] = {q0.x, q0.w, q1.z, q2.y};
        const int ys[4] = {q0.y, q1.x, q1.w, q2.z};
        const int db[4] = {__float_as_int(dp.x), __float_as_int(dp.y),
                           __float_as_int(dp.z), __float_as_int(dp.w)};

        int bins[4], keys[4], idxv[4];
        #pragma unroll
        for (int u = 0; u < 4; ++u) {
            const int x = xs[u], y = ys[u];
            const bool ok = (unsigned)x < (unsigned)NVX &&
                            (unsigned)y < (unsigned)NVY;
            const int p  = p0 + u;
            const int b  = (p >= NDHW) ? 1 : 0;       // B == 2
            const int v  = (b * NVY + y) * NVX + x;
            const int bn = (unsigned)p / (unsigned)DHW;
            const int hw = (unsigned)p % (unsigned)HW;
            bins[u] = v & 511;                        // uniform within block
            keys[u] = (v << 14) | (bn * HW + hw);     // v:15b | row:14b
            idxv[u] = ok ? -1 : -2;
        }
        #pragma unroll
        for (int u = 0; u < 4; ++u)                   // independent LDS atomics
            if (idxv[u] == -1) idxv[u] = atomicAdd(&bcnt[bins[u]], 1);
        #pragma unroll
        for (int u = 0; u < 4; ++u)
            if ((unsigned)idxv[u] < (unsigned)CAP)
                stage[bins[u] * SLOT + idxv[u]] = make_int2(keys[u], db[u]);
        #pragma unroll
        for (int u = 0; u < 4; ++u) {                 // wave-aggregated spill
            const bool sp = (idxv[u] >= CAP);
            const unsigned long long m = __ballot(sp);
            if (m) {
                const int leader = (int)__ffsll((unsigned long long)m) - 1;
                int base = 0;
                if (lane == leader) base = atomicAdd(spillcnt, (int)__popcll(m));
                base = __shfl(base, leader);
                if (sp) {
                    const int off = base +
                        (int)__popcll(m & ((1ull << lane) - 1ull));
                    if (off < SPILLCAP) spill[off] = make_int2(keys[u], db[u]);
                }
            }
        }
        __syncthreads();
        stage[t * SLOT + CAP].x = bcnt[t];            // counts in slot 7
        stage[(t + 256) * SLOT + CAP].x = bcnt[t + 256];
        __syncthreads();

        // stream out 2048 int4: each slice = 4 int4 = one full 64B line
        const int4* src = (const int4*)stage;
        int4* dst = (int4*)staging;
        #pragma unroll
        for (int k = 0; k < 8; ++k) {
            const int i  = k * 256 + t;           // 0..2047
            const int sl = i >> 2, part = i & 3;  // 4 int4 per slice
            dst[((size_t)sl * SCAN_BLOCKS + blockIdx.x) * 4 + part] = src[i];
        }
    } else {
        // transpose ctx (bn, c, hw) -> ctx_t (bn*HW + hw, c), 16c x 64hw tiles
        const int tb  = blockIdx.x - SCAN_BLOCKS;
        const int bn  = tb / 55;
        const int rem = tb % 55;
        const int c0  = (rem / 11) * 16;
        const int hw0 = (rem % 11) * 64;
        const int cl = t >> 6, hwl = t & 63;
        #pragma unroll
        for (int r = 0; r < 4; ++r) {
            const int c = r * 4 + cl;
            tile[c * 68 + hwl] =
                ctx[(size_t)(bn * C + c0 + c) * HW + hw0 + hwl];
        }
        __syncthreads();
        const int cr = t & 15, hwr = t >> 4;
        #pragma unroll
        for (int r = 0; r < 4; ++r) {
            const int hw = r * 16 + hwr;
            ctx_t[(size_t)(bn * HW + hw0 + hw) * C + c0 + cr] =
                tile[cr * 68 + hw];
        }
    }
}

// ---- 2. acc: bucket (prefetched) + spill fold + register accumulate ----
__global__ __launch_bounds__(1024) void acc_kernel(
    const int2* __restrict__ staging, const float* __restrict__ ctx_t,
    float* __restrict__ out, const int* __restrict__ spillcnt,
    const int2* __restrict__ spill)
{
    __shared__ int2 list[VPB * VCAP];   // 29184 B -> 2 blocks/CU
    __shared__ int  vcnt[VPB];
    __shared__ int  ocnt;
    __shared__ int2 olist[OCAP];

    const int bin  = blockIdx.x;
    const int t    = threadIdx.x;
    const int wave = t >> 6, lane = t & 63;

    if (t < VPB) vcnt[t] = 0;
    if (t == 0) ocnt = 0;
    __syncthreads();

    // ---- phase 1: bucket, 8 slices per 64-lane read, 1-deep prefetch.
    const int g = lane >> 3, slot = lane & 7;
    constexpr int NCH = (SCAN_BLOCKS + 7) / 8;   // 116 chunks
    {
        const int s0 = wave * 8 + g;
        int2 e_nxt = make_int2(0, 0);
        if (s0 < SCAN_BLOCKS)
            e_nxt = staging[((size_t)bin * SCAN_BLOCKS + s0) * SLOT + slot];
        for (int c = wave; c < NCH; c += 16) {
            const int2 e = e_nxt;
            const int c2 = c + 16;
            if (c2 < NCH) {                      // prefetch next chunk
                const int s2 = c2 * 8 + g;
                e_nxt = (s2 < SCAN_BLOCKS)
                    ? staging[((size_t)bin * SCAN_BLOCKS + s2) * SLOT + slot]
                    : make_int2(0, 0);
            }
            const int s = c * 8 + g;
            int cnt = __shfl(e.x, (lane & 56) | CAP);   // slot7.x = count
            cnt = cnt < CAP ? cnt : CAP;
            if (s < SCAN_BLOCKS && slot < cnt) {
                const int vl  = e.x >> 23;       // v>>9 (key = v<<14|row)
                const int idx = atomicAdd(&vcnt[vl], 1);
                if (idx < VCAP) list[vl * VCAP + idx] = e;
                else { int o = atomicAdd(&ocnt, 1); if (o < OCAP) olist[o] = e; }
            }
        }
    }
    // ---- fold global scan-spills belonging to this bin (~700 entries total)
    {
        int scnt = *spillcnt;
        scnt = scnt < SPILLCAP ? scnt : SPILLCAP;
        for (int i = t; i < scnt; i += 1024) {
            const int2 e = spill[i];
            if (((e.x >> 14) & 511) == bin) {
                const int vl  = e.x >> 23;
                const int idx = atomicAdd(&vcnt[vl], 1);
                if (idx < VCAP) list[vl * VCAP + idx] = e;
                else { int o = atomicAdd(&ocnt, 1); if (o < OCAP) olist[o] = e; }
            }
        }
    }
    __syncthreads();

    // ---- phase 2: register accumulation, 4 voxels per wave, 8 chains.
    const int off2 = 64 + (lane & 15);           // channels 64..79
    for (int vv = 0; vv < VPB / 16; ++vv) {
        const int vl = wave * (VPB / 16) + vv;
        int n = vcnt[vl];
        n = n < VCAP ? n : VCAP;
        const int2* lp = list + vl * VCAP;

        float a0 = 0.f, a1 = 0.f, a2 = 0.f, a3 = 0.f;
        float a4 = 0.f, a5 = 0.f, a6 = 0.f, a7 = 0.f;
        float b0 = 0.f, b1 = 0.f, b2 = 0.f, b3 = 0.f;
        float b4 = 0.f, b5 = 0.f, b6 = 0.f, b7 = 0.f;
        int j = 0;
        for (; j + 8 <= n; j += 8) {             // 16 L2 loads in flight
            const int2 e0 = lp[j],     e1 = lp[j + 1], e2 = lp[j + 2], e3 = lp[j + 3];
            const int2 e4 = lp[j + 4], e5 = lp[j + 5], e6 = lp[j + 6], e7 = lp[j + 7];
            const float* c0 = ctx_t + (size_t)(e0.x & 16383) * C;
            const float* c1 = ctx_t + (size_t)(e1.x & 16383) * C;
            const float* c2 = ctx_t + (size_t)(e2.x & 16383) * C;
            const float* c3 = ctx_t + (size_t)(e3.x & 16383) * C;
            const float* c4 = ctx_t + (size_t)(e4.x & 16383) * C;
            const float* c5 = ctx_t + (size_t)(e5.x & 16383) * C;
            const float* c6 = ctx_t + (size_t)(e6.x & 16383) * C;
            const float* c7 = ctx_t + (size_t)(e7.x & 16383) * C;
            const float f0 = c0[lane], f1 = c1[lane], f2 = c2[lane], f3 = c3[lane];
            const float f4 = c4[lane], f5 = c5[lane], f6 = c6[lane], f7 = c7[lane];
            const float g0 = c0[off2], g1 = c1[off2], g2 = c2[off2], g3 = c3[off2];
            const float g4 = c4[off2], g5 = c5[off2], g6 = c6[off2], g7 = c7[off2];
            const float w0 = __int_as_float(e0.y), w1 = __int_as_float(e1.y);
            const float w2 = __int_as_float(e2.y), w3 = __int_as_float(e3.y);
            const float w4 = __int_as_float(e4.y), w5 = __int_as_float(e5.y);
            const float w6 = __int_as_float(e6.y), w7 = __int_as_float(e7.y);
            a0 += w0 * f0; a1 += w1 * f1; a2 += w2 * f2; a3 += w3 * f3;
            a4 += w4 * f4; a5 += w5 * f5; a6 += w6 * f6; a7 += w7 * f7;
            b0 += w0 * g0; b1 += w1 * g1; b2 += w2 * g2; b3 += w3 * g3;
            b4 += w4 * g4; b5 += w5 * g5; b6 += w6 * g6; b7 += w7 * g7;
        }
        for (; j + 4 <= n; j += 4) {
            const int2 e0 = lp[j], e1 = lp[j + 1], e2 = lp[j + 2], e3 = lp[j + 3];
            const float* c0 = ctx_t + (size_t)(e0.x & 16383) * C;
            const float* c1 = ctx_t + (size_t)(e1.x & 16383) * C;
            const float* c2 = ctx_t + (size_t)(e2.x & 16383) * C;
            const float* c3 = ctx_t + (size_t)(e3.x & 16383) * C;
            const float f0 = c0[lane], f1 = c1[lane], f2 = c2[lane], f3 = c3[lane];
            const float g0 = c0[off2], g1 = c1[off2], g2 = c2[off2], g3 = c3[off2];
            const float w0 = __int_as_float(e0.y), w1 = __int_as_float(e1.y);
            const float w2 = __int_as_float(e2.y), w3 = __int_as_float(e3.y);
            a0 += w0 * f0; a1 += w1 * f1; a2 += w2 * f2; a3 += w3 * f3;
            b0 += w0 * g0; b1 += w1 * g1; b2 += w2 * g2; b3 += w3 * g3;
        }
        for (; j < n; ++j) {
            const int2 e = lp[j];
            const float* c = ctx_t + (size_t)(e.x & 16383) * C;
            const float w = __int_as_float(e.y);
            a0 += w * c[lane];
            b0 += w * c[off2];
        }
        const float av = ((a0 + a1) + (a2 + a3)) + ((a4 + a5) + (a6 + a7));
        const float bv = ((b0 + b1) + (b2 + b3)) + ((b4 + b5) + (b6 + b7));
        float* o = out + (size_t)((vl << 9) | bin) * C;   // v = vl<<9 | bin
        o[lane] = av;
        if (lane < 16) o[64 + lane] = bv;
    }
    __syncthreads();

    // ---- phase 3: overflow fixup (block owns this bin's output rows) ----
    if (wave == 0) {
        int oc = ocnt;
        oc = oc < OCAP ? oc : OCAP;
        for (int i = 0; i < oc; ++i) {
            const int2 e = olist[i];
            const int vl = e.x >> 23, row = e.x & 16383;
            const float dep = __int_as_float(e.y);
            const float* c = ctx_t + (size_t)row * C;
            float* o = out + (size_t)((vl << 9) | bin) * C;
            unsafeAtomicAdd(o + lane, dep * c[lane]);
            if (lane < 16) unsafeAtomicAdd(o + 64 + lane, dep * c[64 + lane]);
        }
    }
}

extern "C" void kernel_launch(void* const* d_in, const int* in_sizes, int n_in,
                              void* d_out, int out_size, void* d_ws, size_t ws_size,
                              hipStream_t stream) {
    const int*   geom  = (const int*)d_in[0];
    const float* depth = (const float*)d_in[1];
    const float* ctx   = (const float*)d_in[2];
    float*       out   = (float*)d_out;

    // Workspace (~33.5 MB, all segments 256B-multiple):
    char* ws = (char*)d_ws;
    int2* staging  = (int2*)ws; ws += (size_t)NBIN * SCAN_BLOCKS * SLOT * 8; // 30,277,632
    int2* spill    = (int2*)ws; ws += (size_t)SPILLCAP * 8;                  //    524,288
    int*  spillcnt = (int*)ws;  ws += 256;
    float* ctx_t   = (float*)ws;                                             //  2,703,360

    hipMemsetAsync(spillcnt, 0, 256, stream);

    pre_kernel<<<dim3(PRE_BLOCKS), dim3(256),  0, stream>>>(
                  geom, depth, ctx, ctx_t, staging, spillcnt, spill);
    acc_kernel<<<dim3(NBIN),       dim3(1024), 0, stream>>>(
                  staging, ctx_t, out, spillcnt, spill);
}